// Round 3
// baseline (1164.416 us; speedup 1.0000x reference)
//
#include <hip/hip_runtime.h>
#include <cstddef>

#define N_NODES 100000
#define N_EDGES 1600000

// ============ CSR build ============
__global__ __launch_bounds__(256) void k_hist(const int* __restrict__ dst,
                                              int* __restrict__ cursor) {
  int e = blockIdx.x * 256 + threadIdx.x;
  if (e < N_EDGES) atomicAdd(&cursor[dst[e]], 1);
}

__global__ __launch_bounds__(256) void k_alloc(int* __restrict__ cursor,
                                               int* __restrict__ row_start,
                                               int* __restrict__ gcursor) {
  __shared__ int s[256];
  __shared__ int base;
  int i = blockIdx.x * 256 + threadIdx.x;
  int t = threadIdx.x;
  int v = (i < N_NODES) ? cursor[i] : 0;
  s[t] = v;
  __syncthreads();
#pragma unroll
  for (int off = 1; off < 256; off <<= 1) {
    int tmp = (t >= off) ? s[t - off] : 0;
    __syncthreads();
    s[t] += tmp;
    __syncthreads();
  }
  if (t == 255) base = atomicAdd(gcursor, s[255]);
  __syncthreads();
  if (i < N_NODES) {
    int start = base + s[t] - v;  // exclusive scan
    row_start[i] = start;
    cursor[i] = start;
  }
}

__global__ __launch_bounds__(256) void k_fill(const int* __restrict__ src,
                                              const int* __restrict__ dst,
                                              int* __restrict__ cursor,
                                              int* __restrict__ csr_src) {
  int e = blockIdx.x * 256 + threadIdx.x;
  if (e >= N_EDGES) return;
  int pos = atomicAdd(&cursor[dst[e]], 1);
  csr_src[pos] = src[e];
}
// After k_fill: cursor[n] == segment end for node n.

// ============ layer 1: pull-aggregate x (Fin=4), thread per node ============
__global__ __launch_bounds__(256) void k_pull4(
    const float* __restrict__ x, const int* __restrict__ row_start,
    const int* __restrict__ row_end, const int* __restrict__ csr_src,
    float* __restrict__ agg1) {
  int n = blockIdx.x * 256 + threadIdx.x;
  if (n >= N_NODES) return;
  int rs = row_start[n], re = row_end[n];
  float4 acc = make_float4(0.f, 0.f, 0.f, 0.f);
  for (int i = rs; i < re; ++i) {
    int s = csr_src[i];
    float4 v = *(const float4*)(x + (size_t)s * 4);
    acc.x += v.x; acc.y += v.y; acc.z += v.z; acc.w += v.w;
  }
  *(float4*)(agg1 + (size_t)n * 4) = acc;
}

// ============ layer 1 dense: h1 = relu(agg1@W1_rel.T + b1 + x@W1_root.T) ====
__global__ __launch_bounds__(256) void k_layer1(
    const float* __restrict__ x, const float* __restrict__ agg1,
    const float* __restrict__ W1_rel, const float* __restrict__ b1,
    const float* __restrict__ W1_root, float* __restrict__ h1) {
  int tid = blockIdx.x * 256 + threadIdx.x;
  if (tid >= N_NODES * 128) return;
  int node = tid >> 7;
  int f = tid & 127;
  float4 a  = *(const float4*)(agg1 + node * 4);
  float4 xv = *(const float4*)(x + node * 4);
  float4 wr = *(const float4*)(W1_rel + f * 4);
  float4 wo = *(const float4*)(W1_root + f * 4);
  float v = b1[f]
      + a.x  * wr.x + a.y  * wr.y + a.z  * wr.z + a.w  * wr.w
      + xv.x * wo.x + xv.y * wo.y + xv.z * wo.z + xv.w * wo.w;
  h1[tid] = fmaxf(v, 0.0f);
}

// ============ layer 2: pull-aggregate h1 (F=128), one WAVE per node =========
// Wave-cooperative: lane l preloads csr_src[chunk+l] once (coalesced), then
// __shfl-broadcasts each edge index; 4 independent row-gathers in flight.
__global__ __launch_bounds__(256) void k_pull128(
    const float* __restrict__ h1, const int* __restrict__ row_start,
    const int* __restrict__ row_end, const int* __restrict__ csr_src,
    float* __restrict__ agg2) {
  int w = (blockIdx.x * 256 + threadIdx.x) >> 6;
  if (w >= N_NODES) return;
  int lane = threadIdx.x & 63;
  int rs = row_start[w], re = row_end[w];
  const float2* hb = (const float2*)h1 + lane;  // row stride 64 float2s
  float ax = 0.f, ay = 0.f;
  for (int chunk = rs; chunk < re; chunk += 64) {
    int nv = min(64, re - chunk);
    int sv = (chunk + lane < re) ? csr_src[chunk + lane] : 0;
    int j = 0;
    for (; j + 4 <= nv; j += 4) {
      int s0 = __shfl(sv, j);
      int s1 = __shfl(sv, j + 1);
      int s2 = __shfl(sv, j + 2);
      int s3 = __shfl(sv, j + 3);
      float2 v0 = hb[(size_t)s0 * 64];
      float2 v1 = hb[(size_t)s1 * 64];
      float2 v2 = hb[(size_t)s2 * 64];
      float2 v3 = hb[(size_t)s3 * 64];
      ax += v0.x + v1.x + v2.x + v3.x;
      ay += v0.y + v1.y + v2.y + v3.y;
    }
    for (; j < nv; ++j) {
      int s0 = __shfl(sv, j);
      float2 v0 = hb[(size_t)s0 * 64];
      ax += v0.x; ay += v0.y;
    }
  }
  ((float2*)agg2)[(size_t)w * 64 + lane] = make_float2(ax, ay);
}

// ====== layer 2 dense + mean-pool partial: gsum[f] += relu(...) over nodes ==
// grid = (320, 4): 1280 blocks = 5 blocks/CU (LDS-capped: 5 x 32KB = 160KB).
// Each thread: 2 features (f, f+16) x 4 nodes -> 8 accumulators; the 4 global
// float4 loads per k-chunk feed 32 FMAs.
__global__ __launch_bounds__(256) void k_layer2pool(
    const float* __restrict__ h1, const float* __restrict__ agg2,
    const float* __restrict__ W2_rel, const float* __restrict__ b2,
    const float* __restrict__ W2_root, float* __restrict__ gsum) {
  __shared__ float lds_w[256 * 32];   // [k][f_local], 32 KB
  int tid = threadIdx.x;
  int f0 = blockIdx.y * 32;

  {  // stage weights transposed: lds_w[k][fl] = Wcat[f0+fl][k]
     // lane-minor fl => consecutive lanes hit consecutive banks (no conflict)
    int fl = tid & 31;
    int q  = tid >> 5;   // k-chunk of 32
    int fg = f0 + fl;
    const float* wsrc = (q < 4) ? (W2_rel + fg * 128 + q * 32)
                                : (W2_root + fg * 128 + (q - 4) * 32);
    int kbase = q * 32;
#pragma unroll
    for (int j = 0; j < 32; j += 4) {
      float4 w = *(const float4*)(wsrc + j);
      lds_w[(kbase + j + 0) * 32 + fl] = w.x;
      lds_w[(kbase + j + 1) * 32 + fl] = w.y;
      lds_w[(kbase + j + 2) * 32 + fl] = w.z;
      lds_w[(kbase + j + 3) * 32 + fl] = w.w;
    }
  }
  __syncthreads();

  int f = tid & 15;    // features f and f+16
  int g = tid >> 4;    // 0..15 node sub-group
  float bias0 = b2[f0 + f];
  float bias1 = b2[f0 + f + 16];

  int npb = (N_NODES + gridDim.x - 1) / gridDim.x;
  int nstart = blockIdx.x * npb;
  int nend = min(nstart + npb, N_NODES);

  float fsum0 = 0.0f, fsum1 = 0.0f;
  for (int base = nstart + g * 4; base < nend; base += 64) {
    int m0 = base;
    int m1 = min(base + 1, N_NODES - 1);
    int m2 = min(base + 2, N_NODES - 1);
    int m3 = min(base + 3, N_NODES - 1);
    float a00 = bias0, a01 = bias0, a02 = bias0, a03 = bias0;
    float a10 = bias1, a11 = bias1, a12 = bias1, a13 = bias1;

    const float* A0 = agg2 + (size_t)m0 * 128;
    const float* A1 = agg2 + (size_t)m1 * 128;
    const float* A2 = agg2 + (size_t)m2 * 128;
    const float* A3 = agg2 + (size_t)m3 * 128;
#pragma unroll 2
    for (int k = 0; k < 128; k += 4) {
      float4 x0 = *(const float4*)(A0 + k);
      float4 x1 = *(const float4*)(A1 + k);
      float4 x2 = *(const float4*)(A2 + k);
      float4 x3 = *(const float4*)(A3 + k);
      float w00 = lds_w[(k + 0) * 32 + f];
      float w01 = lds_w[(k + 1) * 32 + f];
      float w02 = lds_w[(k + 2) * 32 + f];
      float w03 = lds_w[(k + 3) * 32 + f];
      float w10 = lds_w[(k + 0) * 32 + f + 16];
      float w11 = lds_w[(k + 1) * 32 + f + 16];
      float w12 = lds_w[(k + 2) * 32 + f + 16];
      float w13 = lds_w[(k + 3) * 32 + f + 16];
      a00 += x0.x * w00 + x0.y * w01 + x0.z * w02 + x0.w * w03;
      a01 += x1.x * w00 + x1.y * w01 + x1.z * w02 + x1.w * w03;
      a02 += x2.x * w00 + x2.y * w01 + x2.z * w02 + x2.w * w03;
      a03 += x3.x * w00 + x3.y * w01 + x3.z * w02 + x3.w * w03;
      a10 += x0.x * w10 + x0.y * w11 + x0.z * w12 + x0.w * w13;
      a11 += x1.x * w10 + x1.y * w11 + x1.z * w12 + x1.w * w13;
      a12 += x2.x * w10 + x2.y * w11 + x2.z * w12 + x2.w * w13;
      a13 += x3.x * w10 + x3.y * w11 + x3.z * w12 + x3.w * w13;
    }
    const float* H0 = h1 + (size_t)m0 * 128;
    const float* H1 = h1 + (size_t)m1 * 128;
    const float* H2 = h1 + (size_t)m2 * 128;
    const float* H3 = h1 + (size_t)m3 * 128;
#pragma unroll 2
    for (int k = 0; k < 128; k += 4) {
      float4 x0 = *(const float4*)(H0 + k);
      float4 x1 = *(const float4*)(H1 + k);
      float4 x2 = *(const float4*)(H2 + k);
      float4 x3 = *(const float4*)(H3 + k);
      float w00 = lds_w[(128 + k + 0) * 32 + f];
      float w01 = lds_w[(128 + k + 1) * 32 + f];
      float w02 = lds_w[(128 + k + 2) * 32 + f];
      float w03 = lds_w[(128 + k + 3) * 32 + f];
      float w10 = lds_w[(128 + k + 0) * 32 + f + 16];
      float w11 = lds_w[(128 + k + 1) * 32 + f + 16];
      float w12 = lds_w[(128 + k + 2) * 32 + f + 16];
      float w13 = lds_w[(128 + k + 3) * 32 + f + 16];
      a00 += x0.x * w00 + x0.y * w01 + x0.z * w02 + x0.w * w03;
      a01 += x1.x * w00 + x1.y * w01 + x1.z * w02 + x1.w * w03;
      a02 += x2.x * w00 + x2.y * w01 + x2.z * w02 + x2.w * w03;
      a03 += x3.x * w00 + x3.y * w01 + x3.z * w02 + x3.w * w03;
      a10 += x0.x * w10 + x0.y * w11 + x0.z * w12 + x0.w * w13;
      a11 += x1.x * w10 + x1.y * w11 + x1.z * w12 + x1.w * w13;
      a12 += x2.x * w10 + x2.y * w11 + x2.z * w12 + x2.w * w13;
      a13 += x3.x * w10 + x3.y * w11 + x3.z * w12 + x3.w * w13;
    }
    if (base + 0 < nend) { fsum0 += fmaxf(a00, 0.0f); fsum1 += fmaxf(a10, 0.0f); }
    if (base + 1 < nend) { fsum0 += fmaxf(a01, 0.0f); fsum1 += fmaxf(a11, 0.0f); }
    if (base + 2 < nend) { fsum0 += fmaxf(a02, 0.0f); fsum1 += fmaxf(a12, 0.0f); }
    if (base + 3 < nend) { fsum0 += fmaxf(a03, 0.0f); fsum1 += fmaxf(a13, 0.0f); }
  }
  atomicAdd(gsum + f0 + f, fsum0);
  atomicAdd(gsum + f0 + f + 16, fsum1);
}

// ============ head: out = (gsum/N) @ Wlin.T + blin ============
__global__ void k_final(const float* __restrict__ gsum, const float* __restrict__ Wlin,
                        const float* __restrict__ blin, float* __restrict__ out) {
  int lane = threadIdx.x;  // 64 threads
  float g0 = gsum[lane];
  float g1 = gsum[lane + 64];
  float s0 = g0 * Wlin[lane]       + g1 * Wlin[lane + 64];
  float s1 = g0 * Wlin[128 + lane] + g1 * Wlin[192 + lane];
#pragma unroll
  for (int off = 32; off > 0; off >>= 1) {
    s0 += __shfl_down(s0, off);
    s1 += __shfl_down(s1, off);
  }
  if (lane == 0) {
    const float inv = 1.0f / (float)N_NODES;
    out[0] = s0 * inv + blin[0];
    out[1] = s1 * inv + blin[1];
  }
}

extern "C" void kernel_launch(void* const* d_in, const int* in_sizes, int n_in,
                              void* d_out, int out_size, void* d_ws, size_t ws_size,
                              hipStream_t stream) {
  const float* x       = (const float*)d_in[0];
  const int*   ei      = (const int*)d_in[1];
  const float* W1_rel  = (const float*)d_in[2];
  const float* b1      = (const float*)d_in[3];
  const float* W1_root = (const float*)d_in[4];
  const float* W2_rel  = (const float*)d_in[5];
  const float* b2      = (const float*)d_in[6];
  const float* W2_root = (const float*)d_in[7];
  const float* Wlin    = (const float*)d_in[8];
  const float* blin    = (const float*)d_in[9];
  const int* src = ei;            // edge_index[0]
  const int* dst = ei + N_EDGES;  // edge_index[1]
  float* out = (float*)d_out;

  // workspace layout (bytes): see R2 — row_start|cursor|gcursor|gsum|csr_src|h1|agg2
  char* ws = (char*)d_ws;
  int*   row_start = (int*)(ws);
  int*   cursor    = (int*)(ws + 400000);
  int*   gcursor   = (int*)(ws + 800000);
  float* gsum      = (float*)(ws + 800128);
  int*   csr_src   = (int*)(ws + 800768);
  float* h1        = (float*)(ws + 7200768);
  float* agg2      = (float*)(ws + 58400768);
  float* agg1      = agg2;  // overlay: dead before agg2 is written

  hipMemsetAsync(cursor, 0, 400000, stream);
  hipMemsetAsync(gcursor, 0, 128, stream);
  hipMemsetAsync(gsum, 0, 512, stream);

  k_hist <<<(N_EDGES + 255) / 256, 256, 0, stream>>>(dst, cursor);
  k_alloc<<<(N_NODES + 255) / 256, 256, 0, stream>>>(cursor, row_start, gcursor);
  k_fill <<<(N_EDGES + 255) / 256, 256, 0, stream>>>(src, dst, cursor, csr_src);
  k_pull4<<<(N_NODES + 255) / 256, 256, 0, stream>>>(x, row_start, cursor, csr_src, agg1);
  k_layer1<<<(N_NODES * 128 + 255) / 256, 256, 0, stream>>>(x, agg1, W1_rel, b1, W1_root, h1);
  k_pull128<<<(N_NODES * 64 + 255) / 256, 256, 0, stream>>>(h1, row_start, cursor, csr_src, agg2);
  k_layer2pool<<<dim3(320, 4), 256, 0, stream>>>(h1, agg2, W2_rel, b2, W2_root, gsum);
  k_final<<<1, 64, 0, stream>>>(gsum, Wlin, blin, out);
}

// Round 4
// 650.465 us; speedup vs baseline: 1.7901x; 1.7901x over previous
//
#include <hip/hip_runtime.h>
#include <cstddef>

#define N_NODES 100000
#define N_EDGES 1600000
#define NCHUNK 1563   // ceil(N_NODES / 64)

typedef __attribute__((ext_vector_type(8))) short short8;   // 8 bf16 = 4 VGPRs
typedef __attribute__((ext_vector_type(4))) float f32x4;

// round-to-nearest-even f32 -> bf16 pair, packed low|high
__device__ __forceinline__ unsigned pack_bf16x2(float a, float b) {
  unsigned ua = __float_as_uint(a); ua += 0x7FFFu + ((ua >> 16) & 1u);
  unsigned ub = __float_as_uint(b); ub += 0x7FFFu + ((ub >> 16) & 1u);
  return (ua >> 16) | (ub & 0xFFFF0000u);
}

// ============ CSR build ============
__global__ __launch_bounds__(256) void k_hist(const int* __restrict__ dst,
                                              int* __restrict__ cursor) {
  int e = blockIdx.x * 256 + threadIdx.x;
  if (e < N_EDGES) atomicAdd(&cursor[dst[e]], 1);
}

__global__ __launch_bounds__(256) void k_alloc(int* __restrict__ cursor,
                                               int* __restrict__ row_start,
                                               int* __restrict__ gcursor) {
  __shared__ int s[256];
  __shared__ int base;
  int i = blockIdx.x * 256 + threadIdx.x;
  int t = threadIdx.x;
  int v = (i < N_NODES) ? cursor[i] : 0;
  s[t] = v;
  __syncthreads();
#pragma unroll
  for (int off = 1; off < 256; off <<= 1) {
    int tmp = (t >= off) ? s[t - off] : 0;
    __syncthreads();
    s[t] += tmp;
    __syncthreads();
  }
  if (t == 255) base = atomicAdd(gcursor, s[255]);
  __syncthreads();
  if (i < N_NODES) {
    int start = base + s[t] - v;  // exclusive scan
    row_start[i] = start;
    cursor[i] = start;
  }
}

__global__ __launch_bounds__(256) void k_fill(const int* __restrict__ src,
                                              const int* __restrict__ dst,
                                              int* __restrict__ cursor,
                                              int* __restrict__ csr_src) {
  int e = blockIdx.x * 256 + threadIdx.x;
  if (e >= N_EDGES) return;
  int pos = atomicAdd(&cursor[dst[e]], 1);
  csr_src[pos] = src[e];
}
// After k_fill: cursor[n] == segment end for node n.

// ============ layer 1: pull-aggregate x (Fin=4), thread per node ============
__global__ __launch_bounds__(256) void k_pull4(
    const float* __restrict__ x, const int* __restrict__ row_start,
    const int* __restrict__ row_end, const int* __restrict__ csr_src,
    float* __restrict__ agg1) {
  int n = blockIdx.x * 256 + threadIdx.x;
  if (n >= N_NODES) return;
  int rs = row_start[n], re = row_end[n];
  float4 acc = make_float4(0.f, 0.f, 0.f, 0.f);
  for (int i = rs; i < re; ++i) {
    int s = csr_src[i];
    float4 v = *(const float4*)(x + (size_t)s * 4);
    acc.x += v.x; acc.y += v.y; acc.z += v.z; acc.w += v.w;
  }
  *(float4*)(agg1 + (size_t)n * 4) = acc;
}

// ====== layer 1 dense: h1 = relu(...) computed fp32, stored bf16 rows ======
// thread handles 2 features -> one packed uint store (coalesced 4B/lane)
__global__ __launch_bounds__(256) void k_layer1(
    const float* __restrict__ x, const float* __restrict__ agg1,
    const float* __restrict__ W1_rel, const float* __restrict__ b1,
    const float* __restrict__ W1_root, unsigned* __restrict__ h1b) {
  int tid = blockIdx.x * 256 + threadIdx.x;
  if (tid >= N_NODES * 64) return;
  int node = tid >> 6;
  int f = (tid & 63) * 2;
  float4 a  = *(const float4*)(agg1 + node * 4);
  float4 xv = *(const float4*)(x + node * 4);
  float4 wr0 = *(const float4*)(W1_rel + f * 4);
  float4 wo0 = *(const float4*)(W1_root + f * 4);
  float4 wr1 = *(const float4*)(W1_rel + (f + 1) * 4);
  float4 wo1 = *(const float4*)(W1_root + (f + 1) * 4);
  float v0 = b1[f]
      + a.x * wr0.x + a.y * wr0.y + a.z * wr0.z + a.w * wr0.w
      + xv.x * wo0.x + xv.y * wo0.y + xv.z * wo0.z + xv.w * wo0.w;
  float v1 = b1[f + 1]
      + a.x * wr1.x + a.y * wr1.y + a.z * wr1.z + a.w * wr1.w
      + xv.x * wo1.x + xv.y * wo1.y + xv.z * wo1.z + xv.w * wo1.w;
  h1b[tid] = pack_bf16x2(fmaxf(v0, 0.f), fmaxf(v1, 0.f));
}

// ============ layer 2 aggregate: pull bf16 h1 rows, one WAVE per node ======
// lane reads one uint (2 bf16 features) per edge: 256B/row per wave.
__global__ __launch_bounds__(256) void k_pull128(
    const unsigned* __restrict__ h1b, const int* __restrict__ row_start,
    const int* __restrict__ row_end, const int* __restrict__ csr_src,
    unsigned* __restrict__ agg2b) {
  int w = (blockIdx.x * 256 + threadIdx.x) >> 6;
  if (w >= N_NODES) return;
  int lane = threadIdx.x & 63;
  int rs = row_start[w], re = row_end[w];
  float ax = 0.f, ay = 0.f;
  for (int chunk = rs; chunk < re; chunk += 64) {
    int nv = min(64, re - chunk);
    int sv = (chunk + lane < re) ? csr_src[chunk + lane] : 0;
    int j = 0;
    for (; j + 4 <= nv; j += 4) {
      int s0 = __shfl(sv, j);
      int s1 = __shfl(sv, j + 1);
      int s2 = __shfl(sv, j + 2);
      int s3 = __shfl(sv, j + 3);
      unsigned u0 = h1b[(size_t)s0 * 64 + lane];
      unsigned u1 = h1b[(size_t)s1 * 64 + lane];
      unsigned u2 = h1b[(size_t)s2 * 64 + lane];
      unsigned u3 = h1b[(size_t)s3 * 64 + lane];
      ax += __uint_as_float(u0 << 16) + __uint_as_float(u1 << 16)
          + __uint_as_float(u2 << 16) + __uint_as_float(u3 << 16);
      ay += __uint_as_float(u0 & 0xFFFF0000u) + __uint_as_float(u1 & 0xFFFF0000u)
          + __uint_as_float(u2 & 0xFFFF0000u) + __uint_as_float(u3 & 0xFFFF0000u);
    }
    for (; j < nv; ++j) {
      int s0 = __shfl(sv, j);
      unsigned u0 = h1b[(size_t)s0 * 64 + lane];
      ax += __uint_as_float(u0 << 16);
      ay += __uint_as_float(u0 & 0xFFFF0000u);
    }
  }
  agg2b[(size_t)w * 64 + lane] = pack_bf16x2(ax, ay);
}

// ====== layer 2 dense + pool: MFMA GEMM [N x 256]@[256 x 128], relu+colsum ==
// wave = 64 nodes (4 M-tiles of 16) x 128 features (8 F-tiles of 16).
// A = [agg2b | h1b] along K, read once from global. B staged bf16 in LDS in
// fragment-contiguous layout: entry(K0,T,L) = W[K0*32+(L>>4)*8+j][T*16+(L&15)].
__global__ __launch_bounds__(256) void k_gemm_pool(
    const unsigned* __restrict__ agg2b_u, const unsigned* __restrict__ h1b_u,
    const float* __restrict__ W2_rel, const float* __restrict__ b2,
    const float* __restrict__ W2_root, float* __restrict__ gsum) {
  __shared__ unsigned short lds_w[32768];  // 64 KB: [8 ksteps][8 ftiles][64 lanes][8 bf16]

  // ---- stage weights (one-time) ----
#pragma unroll
  for (int i = 0; i < 16; ++i) {
    int e = threadIdx.x + i * 256;          // 0..4095
    int L = e & 63, T = (e >> 6) & 7, K0 = e >> 9;
    int f = T * 16 + (L & 15);
    int k0 = K0 * 32 + ((L >> 4) << 3);     // 8-aligned; never crosses 128
    const float* wsrc = (k0 < 128) ? (W2_rel + f * 128 + k0)
                                   : (W2_root + f * 128 + (k0 - 128));
    float4 w0 = *(const float4*)(wsrc);
    float4 w1 = *(const float4*)(wsrc + 4);
    unsigned* d = (unsigned*)&lds_w[e * 8];
    d[0] = pack_bf16x2(w0.x, w0.y);
    d[1] = pack_bf16x2(w0.z, w0.w);
    d[2] = pack_bf16x2(w1.x, w1.y);
    d[3] = pack_bf16x2(w1.z, w1.w);
  }
  __syncthreads();

  int lane = threadIdx.x & 63;
  int gw = blockIdx.x * 4 + (threadIdx.x >> 6);
  int lrow = lane & 15;
  int quad = lane >> 4;
  const unsigned short* agg2b = (const unsigned short*)agg2b_u;
  const unsigned short* h1b   = (const unsigned short*)h1b_u;

  float bias[8];
#pragma unroll
  for (int t = 0; t < 8; ++t) bias[t] = b2[t * 16 + lrow];

  float csum[8] = {0.f, 0.f, 0.f, 0.f, 0.f, 0.f, 0.f, 0.f};

  if (gw < NCHUNK) {
    int mbase = gw * 64;
    int nt = (N_NODES - mbase) >> 4;  // N_NODES % 16 == 0
    if (nt > 4) nt = 4;

    f32x4 acc[4][8];
#pragma unroll
    for (int mt = 0; mt < 4; ++mt)
#pragma unroll
      for (int t = 0; t < 8; ++t) acc[mt][t] = (f32x4){0.f, 0.f, 0.f, 0.f};

#pragma unroll
    for (int ks = 0; ks < 8; ++ks) {
      const unsigned short* abase = (ks < 4)
          ? (agg2b + ks * 32 + quad * 8)
          : (h1b + (ks - 4) * 32 + quad * 8);
      short8 afr[4];
      for (int mt = 0; mt < nt; ++mt) {
        int row = mbase + mt * 16 + lrow;
        afr[mt] = *(const short8*)(abase + (size_t)row * 128);
      }
      const short8* wl = (const short8*)lds_w;
      short8 bfr[8];
#pragma unroll
      for (int t = 0; t < 8; ++t) bfr[t] = wl[(ks * 8 + t) * 64 + lane];
      for (int mt = 0; mt < nt; ++mt)
#pragma unroll
        for (int t = 0; t < 8; ++t)
          acc[mt][t] = __builtin_amdgcn_mfma_f32_16x16x32_bf16(
              afr[mt], bfr[t], acc[mt][t], 0, 0, 0);
    }

    // epilogue: relu + column-sum over the 16 rows of each tile
    for (int mt = 0; mt < nt; ++mt) {
#pragma unroll
      for (int t = 0; t < 8; ++t) {
        f32x4 v = acc[mt][t];
        float s = fmaxf(v.x + bias[t], 0.f) + fmaxf(v.y + bias[t], 0.f)
                + fmaxf(v.z + bias[t], 0.f) + fmaxf(v.w + bias[t], 0.f);
        s += __shfl_xor(s, 16);
        s += __shfl_xor(s, 32);
        csum[t] += s;   // all lanes hold colsum for col = lrow
      }
    }
  }
  if (lane < 16) {
#pragma unroll
    for (int t = 0; t < 8; ++t) atomicAdd(gsum + t * 16 + lane, csum[t]);
  }
}

// ============ head: out = (gsum/N) @ Wlin.T + blin ============
__global__ void k_final(const float* __restrict__ gsum, const float* __restrict__ Wlin,
                        const float* __restrict__ blin, float* __restrict__ out) {
  int lane = threadIdx.x;  // 64 threads
  float g0 = gsum[lane];
  float g1 = gsum[lane + 64];
  float s0 = g0 * Wlin[lane]       + g1 * Wlin[lane + 64];
  float s1 = g0 * Wlin[128 + lane] + g1 * Wlin[192 + lane];
#pragma unroll
  for (int off = 32; off > 0; off >>= 1) {
    s0 += __shfl_down(s0, off);
    s1 += __shfl_down(s1, off);
  }
  if (lane == 0) {
    const float inv = 1.0f / (float)N_NODES;
    out[0] = s0 * inv + blin[0];
    out[1] = s1 * inv + blin[1];
  }
}

extern "C" void kernel_launch(void* const* d_in, const int* in_sizes, int n_in,
                              void* d_out, int out_size, void* d_ws, size_t ws_size,
                              hipStream_t stream) {
  const float* x       = (const float*)d_in[0];
  const int*   ei      = (const int*)d_in[1];
  const float* W1_rel  = (const float*)d_in[2];
  const float* b1      = (const float*)d_in[3];
  const float* W1_root = (const float*)d_in[4];
  const float* W2_rel  = (const float*)d_in[5];
  const float* b2      = (const float*)d_in[6];
  const float* W2_root = (const float*)d_in[7];
  const float* Wlin    = (const float*)d_in[8];
  const float* blin    = (const float*)d_in[9];
  const int* src = ei;            // edge_index[0]
  const int* dst = ei + N_EDGES;  // edge_index[1]
  float* out = (float*)d_out;

  // workspace layout (bytes):
  //   row_start @0         : 400,000
  //   cursor    @400,000   : 400,000
  //   gcursor   @800,000   : 128
  //   gsum      @800,128   : 512
  //   csr_src   @800,768   : 6,400,000   -> 7,200,768
  //   h1b       @7,200,768 : 25,600,000  -> 32,800,768   (bf16 rows of 128)
  //   agg2b     @32,800,768: 25,600,000  -> 58,400,768   (bf16 rows of 128)
  //   agg1      @58,400,768: 1,600,000   -> 60,000,768   (fp32, layer-1 agg)
  char* ws = (char*)d_ws;
  int*      row_start = (int*)(ws);
  int*      cursor    = (int*)(ws + 400000);
  int*      gcursor   = (int*)(ws + 800000);
  float*    gsum      = (float*)(ws + 800128);
  int*      csr_src   = (int*)(ws + 800768);
  unsigned* h1b       = (unsigned*)(ws + 7200768);
  unsigned* agg2b     = (unsigned*)(ws + 32800768);
  float*    agg1      = (float*)(ws + 58400768);

  hipMemsetAsync(cursor, 0, 400000, stream);
  hipMemsetAsync(gcursor, 0, 128, stream);
  hipMemsetAsync(gsum, 0, 512, stream);

  k_hist <<<(N_EDGES + 255) / 256, 256, 0, stream>>>(dst, cursor);
  k_alloc<<<(N_NODES + 255) / 256, 256, 0, stream>>>(cursor, row_start, gcursor);
  k_fill <<<(N_EDGES + 255) / 256, 256, 0, stream>>>(src, dst, cursor, csr_src);
  k_pull4<<<(N_NODES + 255) / 256, 256, 0, stream>>>(x, row_start, cursor, csr_src, agg1);
  k_layer1<<<(N_NODES * 64 + 255) / 256, 256, 0, stream>>>(x, agg1, W1_rel, b1, W1_root, h1b);
  k_pull128<<<(N_NODES * 64 + 255) / 256, 256, 0, stream>>>(h1b, row_start, cursor, csr_src, agg2b);
  k_gemm_pool<<<(NCHUNK + 3) / 4, 256, 0, stream>>>(agg2b, h1b, W2_rel, b2, W2_root, gsum);
  k_final<<<1, 64, 0, stream>>>(gsum, Wlin, blin, out);
}

// Round 5
// 416.167 us; speedup vs baseline: 2.7980x; 1.5630x over previous
//
#include <hip/hip_runtime.h>
#include <cstddef>

#define N_NODES 100000
#define N_EDGES 1600000
#define NCHUNK 1563   // ceil(N_NODES / 64)

typedef __attribute__((ext_vector_type(8))) short short8;   // 8 bf16 = 4 VGPRs
typedef __attribute__((ext_vector_type(4))) float f32x4;

// round-to-nearest-even f32 -> bf16 pair, packed low|high
__device__ __forceinline__ unsigned pack_bf16x2(float a, float b) {
  unsigned ua = __float_as_uint(a); ua += 0x7FFFu + ((ua >> 16) & 1u);
  unsigned ub = __float_as_uint(b); ub += 0x7FFFu + ((ub >> 16) & 1u);
  return (ua >> 16) | (ub & 0xFFFF0000u);
}

// ============ CSR build ============
__global__ __launch_bounds__(256) void k_hist(const int* __restrict__ dst,
                                              int* __restrict__ cursor) {
  int e = blockIdx.x * 256 + threadIdx.x;
  if (e < N_EDGES) atomicAdd(&cursor[dst[e]], 1);
}

__global__ __launch_bounds__(256) void k_alloc(int* __restrict__ cursor,
                                               int* __restrict__ row_start,
                                               int* __restrict__ gcursor) {
  __shared__ int s[256];
  __shared__ int base;
  int i = blockIdx.x * 256 + threadIdx.x;
  int t = threadIdx.x;
  int v = (i < N_NODES) ? cursor[i] : 0;
  s[t] = v;
  __syncthreads();
#pragma unroll
  for (int off = 1; off < 256; off <<= 1) {
    int tmp = (t >= off) ? s[t - off] : 0;
    __syncthreads();
    s[t] += tmp;
    __syncthreads();
  }
  if (t == 255) base = atomicAdd(gcursor, s[255]);
  __syncthreads();
  if (i < N_NODES) {
    int start = base + s[t] - v;  // exclusive scan
    row_start[i] = start;
    cursor[i] = start;
  }
}

__global__ __launch_bounds__(256) void k_fill(const int* __restrict__ src,
                                              const int* __restrict__ dst,
                                              int* __restrict__ cursor,
                                              int* __restrict__ csr_src) {
  int e = blockIdx.x * 256 + threadIdx.x;
  if (e >= N_EDGES) return;
  int pos = atomicAdd(&cursor[dst[e]], 1);
  csr_src[pos] = src[e];
}
// After k_fill: cursor[n] == segment end for node n.

// ============ layer 1: pull-aggregate x (Fin=4), thread per node ============
__global__ __launch_bounds__(256) void k_pull4(
    const float* __restrict__ x, const int* __restrict__ row_start,
    const int* __restrict__ row_end, const int* __restrict__ csr_src,
    float* __restrict__ agg1) {
  int n = blockIdx.x * 256 + threadIdx.x;
  if (n >= N_NODES) return;
  int rs = row_start[n], re = row_end[n];
  float4 acc = make_float4(0.f, 0.f, 0.f, 0.f);
  for (int i = rs; i < re; ++i) {
    int s = csr_src[i];
    float4 v = *(const float4*)(x + (size_t)s * 4);
    acc.x += v.x; acc.y += v.y; acc.z += v.z; acc.w += v.w;
  }
  *(float4*)(agg1 + (size_t)n * 4) = acc;
}

// ====== layer 1 dense: h1 = relu(...) computed fp32, stored bf16 rows ======
__global__ __launch_bounds__(256) void k_layer1(
    const float* __restrict__ x, const float* __restrict__ agg1,
    const float* __restrict__ W1_rel, const float* __restrict__ b1,
    const float* __restrict__ W1_root, unsigned* __restrict__ h1b) {
  int tid = blockIdx.x * 256 + threadIdx.x;
  if (tid >= N_NODES * 64) return;
  int node = tid >> 6;
  int f = (tid & 63) * 2;
  float4 a  = *(const float4*)(agg1 + node * 4);
  float4 xv = *(const float4*)(x + node * 4);
  float4 wr0 = *(const float4*)(W1_rel + f * 4);
  float4 wo0 = *(const float4*)(W1_root + f * 4);
  float4 wr1 = *(const float4*)(W1_rel + (f + 1) * 4);
  float4 wo1 = *(const float4*)(W1_root + (f + 1) * 4);
  float v0 = b1[f]
      + a.x * wr0.x + a.y * wr0.y + a.z * wr0.z + a.w * wr0.w
      + xv.x * wo0.x + xv.y * wo0.y + xv.z * wo0.z + xv.w * wo0.w;
  float v1 = b1[f + 1]
      + a.x * wr1.x + a.y * wr1.y + a.z * wr1.z + a.w * wr1.w
      + xv.x * wo1.x + xv.y * wo1.y + xv.z * wo1.z + xv.w * wo1.w;
  h1b[tid] = pack_bf16x2(fmaxf(v0, 0.f), fmaxf(v1, 0.f));
}

// ============ layer 2 aggregate: pull bf16 h1 rows, one WAVE per node ======
__global__ __launch_bounds__(256) void k_pull128(
    const unsigned* __restrict__ h1b, const int* __restrict__ row_start,
    const int* __restrict__ row_end, const int* __restrict__ csr_src,
    unsigned* __restrict__ agg2b) {
  int w = (blockIdx.x * 256 + threadIdx.x) >> 6;
  if (w >= N_NODES) return;
  int lane = threadIdx.x & 63;
  int rs = row_start[w], re = row_end[w];
  float ax = 0.f, ay = 0.f;
  for (int chunk = rs; chunk < re; chunk += 64) {
    int nv = min(64, re - chunk);
    int sv = (chunk + lane < re) ? csr_src[chunk + lane] : 0;
    int j = 0;
    for (; j + 4 <= nv; j += 4) {
      int s0 = __shfl(sv, j);
      int s1 = __shfl(sv, j + 1);
      int s2 = __shfl(sv, j + 2);
      int s3 = __shfl(sv, j + 3);
      unsigned u0 = h1b[(size_t)s0 * 64 + lane];
      unsigned u1 = h1b[(size_t)s1 * 64 + lane];
      unsigned u2 = h1b[(size_t)s2 * 64 + lane];
      unsigned u3 = h1b[(size_t)s3 * 64 + lane];
      ax += __uint_as_float(u0 << 16) + __uint_as_float(u1 << 16)
          + __uint_as_float(u2 << 16) + __uint_as_float(u3 << 16);
      ay += __uint_as_float(u0 & 0xFFFF0000u) + __uint_as_float(u1 & 0xFFFF0000u)
          + __uint_as_float(u2 & 0xFFFF0000u) + __uint_as_float(u3 & 0xFFFF0000u);
    }
    for (; j < nv; ++j) {
      int s0 = __shfl(sv, j);
      unsigned u0 = h1b[(size_t)s0 * 64 + lane];
      ax += __uint_as_float(u0 << 16);
      ay += __uint_as_float(u0 & 0xFFFF0000u);
    }
  }
  agg2b[(size_t)w * 64 + lane] = pack_bf16x2(ax, ay);
}

// ====== layer 2 dense + pool: MFMA GEMM [N x 256]@[256 x 128], relu+colsum ==
// wave = 64 nodes (4 M-tiles of 16) x 128 features (8 F-tiles of 16).
// ALL register arrays indexed by compile-time constants (R4's runtime-nt
// indexing spilled acc[] to scratch: 438 MB of WRITE traffic). A-row loads
// clamped; per-tile epilogue gated (tiles align: N_NODES % 16 == 0).
__global__ __launch_bounds__(256) void k_gemm_pool(
    const unsigned* __restrict__ agg2b_u, const unsigned* __restrict__ h1b_u,
    const float* __restrict__ W2_rel, const float* __restrict__ b2,
    const float* __restrict__ W2_root, float* __restrict__ gsum) {
  __shared__ unsigned short lds_w[32768];  // 64 KB: [8 ksteps][8 ftiles][64 lanes][8 bf16]

  // ---- stage weights (one-time) ----
#pragma unroll
  for (int i = 0; i < 16; ++i) {
    int e = threadIdx.x + i * 256;          // 0..4095
    int L = e & 63, T = (e >> 6) & 7, K0 = e >> 9;
    int f = T * 16 + (L & 15);
    int k0 = K0 * 32 + ((L >> 4) << 3);     // 8-aligned; never crosses 128
    const float* wsrc = (k0 < 128) ? (W2_rel + f * 128 + k0)
                                   : (W2_root + f * 128 + (k0 - 128));
    float4 w0 = *(const float4*)(wsrc);
    float4 w1 = *(const float4*)(wsrc + 4);
    unsigned* d = (unsigned*)&lds_w[e * 8];
    d[0] = pack_bf16x2(w0.x, w0.y);
    d[1] = pack_bf16x2(w0.z, w0.w);
    d[2] = pack_bf16x2(w1.x, w1.y);
    d[3] = pack_bf16x2(w1.z, w1.w);
  }
  __syncthreads();

  int lane = threadIdx.x & 63;
  int gw = blockIdx.x * 4 + (threadIdx.x >> 6);
  int lrow = lane & 15;
  int quad = lane >> 4;
  const unsigned short* agg2b = (const unsigned short*)agg2b_u;
  const unsigned short* h1b   = (const unsigned short*)h1b_u;

  float bias[8];
#pragma unroll
  for (int t = 0; t < 8; ++t) bias[t] = b2[t * 16 + lrow];

  float csum[8] = {0.f, 0.f, 0.f, 0.f, 0.f, 0.f, 0.f, 0.f};

  if (gw < NCHUNK) {
    int mbase = gw * 64;

    f32x4 acc[4][8];
#pragma unroll
    for (int mt = 0; mt < 4; ++mt)
#pragma unroll
      for (int t = 0; t < 8; ++t) acc[mt][t] = (f32x4){0.f, 0.f, 0.f, 0.f};

#pragma unroll
    for (int ks = 0; ks < 8; ++ks) {
      const unsigned short* abase = (ks < 4)
          ? (agg2b + ks * 32 + quad * 8)
          : (h1b + (ks - 4) * 32 + quad * 8);
      short8 afr[4];
#pragma unroll
      for (int mt = 0; mt < 4; ++mt) {
        int row = mbase + mt * 16 + lrow;
        row = min(row, N_NODES - 1);   // clamp: partial chunk reads row 99999
        afr[mt] = *(const short8*)(abase + (size_t)row * 128);
      }
      const short8* wl = (const short8*)lds_w;
      short8 bfr[8];
#pragma unroll
      for (int t = 0; t < 8; ++t) bfr[t] = wl[(ks * 8 + t) * 64 + lane];
#pragma unroll
      for (int mt = 0; mt < 4; ++mt)
#pragma unroll
        for (int t = 0; t < 8; ++t)
          acc[mt][t] = __builtin_amdgcn_mfma_f32_16x16x32_bf16(
              afr[mt], bfr[t], acc[mt][t], 0, 0, 0);
    }

    // epilogue: relu + column-sum; skip tiles beyond N_NODES (tile-aligned)
#pragma unroll
    for (int mt = 0; mt < 4; ++mt) {
      if (mbase + mt * 16 < N_NODES) {
#pragma unroll
        for (int t = 0; t < 8; ++t) {
          f32x4 v = acc[mt][t];
          float s = fmaxf(v.x + bias[t], 0.f) + fmaxf(v.y + bias[t], 0.f)
                  + fmaxf(v.z + bias[t], 0.f) + fmaxf(v.w + bias[t], 0.f);
          s += __shfl_xor(s, 16);
          s += __shfl_xor(s, 32);
          csum[t] += s;   // all lanes hold colsum for col = lrow
        }
      }
    }
  }
  if (lane < 16) {
#pragma unroll
    for (int t = 0; t < 8; ++t) atomicAdd(gsum + t * 16 + lane, csum[t]);
  }
}

// ============ head: out = (gsum/N) @ Wlin.T + blin ============
__global__ void k_final(const float* __restrict__ gsum, const float* __restrict__ Wlin,
                        const float* __restrict__ blin, float* __restrict__ out) {
  int lane = threadIdx.x;  // 64 threads
  float g0 = gsum[lane];
  float g1 = gsum[lane + 64];
  float s0 = g0 * Wlin[lane]       + g1 * Wlin[lane + 64];
  float s1 = g0 * Wlin[128 + lane] + g1 * Wlin[192 + lane];
#pragma unroll
  for (int off = 32; off > 0; off >>= 1) {
    s0 += __shfl_down(s0, off);
    s1 += __shfl_down(s1, off);
  }
  if (lane == 0) {
    const float inv = 1.0f / (float)N_NODES;
    out[0] = s0 * inv + blin[0];
    out[1] = s1 * inv + blin[1];
  }
}

extern "C" void kernel_launch(void* const* d_in, const int* in_sizes, int n_in,
                              void* d_out, int out_size, void* d_ws, size_t ws_size,
                              hipStream_t stream) {
  const float* x       = (const float*)d_in[0];
  const int*   ei      = (const int*)d_in[1];
  const float* W1_rel  = (const float*)d_in[2];
  const float* b1      = (const float*)d_in[3];
  const float* W1_root = (const float*)d_in[4];
  const float* W2_rel  = (const float*)d_in[5];
  const float* b2      = (const float*)d_in[6];
  const float* W2_root = (const float*)d_in[7];
  const float* Wlin    = (const float*)d_in[8];
  const float* blin    = (const float*)d_in[9];
  const int* src = ei;            // edge_index[0]
  const int* dst = ei + N_EDGES;  // edge_index[1]
  float* out = (float*)d_out;

  // workspace layout (bytes):
  //   row_start @0         : 400,000
  //   cursor    @400,000   : 400,000
  //   gcursor   @800,000   : 128
  //   gsum      @800,128   : 512
  //   csr_src   @800,768   : 6,400,000   -> 7,200,768
  //   h1b       @7,200,768 : 25,600,000  -> 32,800,768   (bf16 rows of 128)
  //   agg2b     @32,800,768: 25,600,000  -> 58,400,768   (bf16 rows of 128)
  //   agg1      @58,400,768: 1,600,000   -> 60,000,768   (fp32, layer-1 agg)
  char* ws = (char*)d_ws;
  int*      row_start = (int*)(ws);
  int*      cursor    = (int*)(ws + 400000);
  int*      gcursor   = (int*)(ws + 800000);
  float*    gsum      = (float*)(ws + 800128);
  int*      csr_src   = (int*)(ws + 800768);
  unsigned* h1b       = (unsigned*)(ws + 7200768);
  unsigned* agg2b     = (unsigned*)(ws + 32800768);
  float*    agg1      = (float*)(ws + 58400768);

  hipMemsetAsync(cursor, 0, 400000, stream);
  hipMemsetAsync(gcursor, 0, 128, stream);
  hipMemsetAsync(gsum, 0, 512, stream);

  k_hist <<<(N_EDGES + 255) / 256, 256, 0, stream>>>(dst, cursor);
  k_alloc<<<(N_NODES + 255) / 256, 256, 0, stream>>>(cursor, row_start, gcursor);
  k_fill <<<(N_EDGES + 255) / 256, 256, 0, stream>>>(src, dst, cursor, csr_src);
  k_pull4<<<(N_NODES + 255) / 256, 256, 0, stream>>>(x, row_start, cursor, csr_src, agg1);
  k_layer1<<<(N_NODES * 64 + 255) / 256, 256, 0, stream>>>(x, agg1, W1_rel, b1, W1_root, h1b);
  k_pull128<<<(N_NODES * 64 + 255) / 256, 256, 0, stream>>>(h1b, row_start, cursor, csr_src, agg2b);
  k_gemm_pool<<<(NCHUNK + 3) / 4, 256, 0, stream>>>(agg2b, h1b, W2_rel, b2, W2_root, gsum);
  k_final<<<1, 64, 0, stream>>>(gsum, Wlin, blin, out);
}

// Round 6
// 294.905 us; speedup vs baseline: 3.9485x; 1.4112x over previous
//
#include <hip/hip_runtime.h>
#include <cstddef>

#define N_NODES 100000
#define N_EDGES 1600000
#define NCHUNK 1563     // ceil(N_NODES / 64)
#define NBUCK 200
#define BUCK_NODES 500
#define BF_EDGES 4096   // edges per k_bfill block
#define BF_BLOCKS ((N_EDGES + BF_EDGES - 1) / BF_EDGES)   // 391

typedef __attribute__((ext_vector_type(8))) short short8;   // 8 bf16 = 4 VGPRs
typedef __attribute__((ext_vector_type(4))) float f32x4;

__device__ __forceinline__ unsigned pack_bf16x2(float a, float b) {
  unsigned ua = __float_as_uint(a); ua += 0x7FFFu + ((ua >> 16) & 1u);
  unsigned ub = __float_as_uint(b); ub += 0x7FFFu + ((ub >> 16) & 1u);
  return (ua >> 16) | (ub & 0xFFFF0000u);
}

// ============ CSR build, bucketed ============
// Pass 1: global bucket counts via per-block LDS histogram.
__global__ __launch_bounds__(256) void k_bhist(const int* __restrict__ dst,
                                               int* __restrict__ bucket_count) {
  __shared__ int lh[NBUCK];
  int t = threadIdx.x;
  if (t < NBUCK) lh[t] = 0;
  __syncthreads();
  int e0 = blockIdx.x * BF_EDGES;
#pragma unroll
  for (int i = 0; i < 16; ++i) {
    int e = e0 + i * 256 + t;
    if (e < N_EDGES) atomicAdd(&lh[dst[e] / BUCK_NODES], 1);
  }
  __syncthreads();
  if (t < NBUCK && lh[t] > 0) atomicAdd(&bucket_count[t], lh[t]);
}

// Pass 2: exclusive scan of 200 bucket counts (1 block).
__global__ __launch_bounds__(256) void k_bscan(const int* __restrict__ bucket_count,
                                               int* __restrict__ bucket_base,
                                               int* __restrict__ bucket_cursor) {
  if (threadIdx.x == 0) {
    int s = 0;
    for (int b = 0; b < NBUCK; ++b) {
      bucket_base[b] = s;
      bucket_cursor[b] = s;
      s += bucket_count[b];
    }
  }
}

// Pass 3: scatter edges into bucket-grouped ebuf. Per-(block,bucket) sub-range
// reserved with ONE global atomic; writes are block-private contiguous chunks.
__global__ __launch_bounds__(256) void k_bfill(const int* __restrict__ src,
                                               const int* __restrict__ dst,
                                               int* __restrict__ bucket_cursor,
                                               uint2* __restrict__ ebuf) {
  __shared__ uint2 stage[BF_EDGES];     // 32 KB
  __shared__ int lh[NBUCK];
  __shared__ int sub_base[NBUCK];
  __shared__ int cur[NBUCK];
  int t = threadIdx.x;
  if (t < NBUCK) { lh[t] = 0; cur[t] = 0; }
  __syncthreads();
  int e0 = blockIdx.x * BF_EDGES;
#pragma unroll
  for (int i = 0; i < 16; ++i) {
    int e = e0 + i * 256 + t;
    uint2 p = make_uint2(0u, 0xFFFFFFFFu);
    if (e < N_EDGES) {
      p = make_uint2((unsigned)src[e], (unsigned)dst[e]);
      atomicAdd(&lh[p.y / BUCK_NODES], 1);
    }
    stage[i * 256 + t] = p;
  }
  __syncthreads();
  if (t < NBUCK) sub_base[t] = (lh[t] > 0) ? atomicAdd(&bucket_cursor[t], lh[t]) : 0;
  __syncthreads();
#pragma unroll
  for (int i = 0; i < 16; ++i) {
    uint2 p = stage[i * 256 + t];
    if (p.y != 0xFFFFFFFFu) {
      int b = p.y / BUCK_NODES;
      int pos = atomicAdd(&cur[b], 1);
      ebuf[sub_base[b] + pos] = p;
    }
  }
}

// Pass 4: one block per bucket. Per-node degree hist + scan in LDS; scatter
// csr_src inside the bucket's contiguous region (single-XCD full-line writes).
__global__ __launch_bounds__(256) void k_fill2(
    const uint2* __restrict__ ebuf, const int* __restrict__ bucket_base,
    const int* __restrict__ bucket_count, int* __restrict__ row_start,
    int* __restrict__ row_end, int* __restrict__ csr_src) {
  __shared__ int cnt[512];
  __shared__ int start[512];
  __shared__ int partial[16];
  int t = threadIdx.x;
  int b = blockIdx.x;
  int base = bucket_base[b];
  int nb = bucket_count[b];
  int n0 = b * BUCK_NODES;
  cnt[t] = 0; cnt[t + 256] = 0;
  __syncthreads();
  // per-node degree histogram
  for (int i = t; i < nb; i += 256) {
    atomicAdd(&cnt[ebuf[base + i].y - n0], 1);
  }
  __syncthreads();
  // exclusive scan of 512 (500 used)
  if (t < 16) {
    int s = 0;
#pragma unroll
    for (int j = 0; j < 32; ++j) { start[t * 32 + j] = s; s += cnt[t * 32 + j]; }
    partial[t] = s;
  }
  __syncthreads();
  if (t == 0) {
    int s = 0;
#pragma unroll
    for (int j = 0; j < 16; ++j) { int tmp = partial[j]; partial[j] = s; s += tmp; }
  }
  __syncthreads();
  if (t < 16) {
    int off = partial[t];
#pragma unroll
    for (int j = 0; j < 32; ++j) start[t * 32 + j] += off;
  }
  __syncthreads();
  // publish row_start, init local cursors (reuse cnt[] as cursor)
  for (int nl = t; nl < BUCK_NODES; nl += 256) {
    row_start[n0 + nl] = base + start[nl];
    cnt[nl] = start[nl];
  }
  __syncthreads();
  // scatter src into csr
  for (int i = t; i < nb; i += 256) {
    uint2 e = ebuf[base + i];
    int p = atomicAdd(&cnt[e.y - n0], 1);
    csr_src[base + p] = (int)e.x;
  }
  __syncthreads();
  for (int nl = t; nl < BUCK_NODES; nl += 256) {
    row_end[n0 + nl] = base + cnt[nl];
  }
}

// ============ layer 1: pull-aggregate x (Fin=4), thread per node ============
__global__ __launch_bounds__(256) void k_pull4(
    const float* __restrict__ x, const int* __restrict__ row_start,
    const int* __restrict__ row_end, const int* __restrict__ csr_src,
    float* __restrict__ agg1) {
  int n = blockIdx.x * 256 + threadIdx.x;
  if (n >= N_NODES) return;
  int rs = row_start[n], re = row_end[n];
  float4 acc = make_float4(0.f, 0.f, 0.f, 0.f);
  for (int i = rs; i < re; ++i) {
    int s = csr_src[i];
    float4 v = *(const float4*)(x + (size_t)s * 4);
    acc.x += v.x; acc.y += v.y; acc.z += v.z; acc.w += v.w;
  }
  *(float4*)(agg1 + (size_t)n * 4) = acc;
}

// ====== layer 1 dense: h1 = relu(...) computed fp32, stored bf16 rows ======
__global__ __launch_bounds__(256) void k_layer1(
    const float* __restrict__ x, const float* __restrict__ agg1,
    const float* __restrict__ W1_rel, const float* __restrict__ b1,
    const float* __restrict__ W1_root, unsigned* __restrict__ h1b) {
  int tid = blockIdx.x * 256 + threadIdx.x;
  if (tid >= N_NODES * 64) return;
  int node = tid >> 6;
  int f = (tid & 63) * 2;
  float4 a  = *(const float4*)(agg1 + node * 4);
  float4 xv = *(const float4*)(x + node * 4);
  float4 wr0 = *(const float4*)(W1_rel + f * 4);
  float4 wo0 = *(const float4*)(W1_root + f * 4);
  float4 wr1 = *(const float4*)(W1_rel + (f + 1) * 4);
  float4 wo1 = *(const float4*)(W1_root + (f + 1) * 4);
  float v0 = b1[f]
      + a.x * wr0.x + a.y * wr0.y + a.z * wr0.z + a.w * wr0.w
      + xv.x * wo0.x + xv.y * wo0.y + xv.z * wo0.z + xv.w * wo0.w;
  float v1 = b1[f + 1]
      + a.x * wr1.x + a.y * wr1.y + a.z * wr1.z + a.w * wr1.w
      + xv.x * wo1.x + xv.y * wo1.y + xv.z * wo1.z + xv.w * wo1.w;
  h1b[tid] = pack_bf16x2(fmaxf(v0, 0.f), fmaxf(v1, 0.f));
}

// ============ layer 2 aggregate: pull bf16 h1 rows, one WAVE per node ======
__global__ __launch_bounds__(256) void k_pull128(
    const unsigned* __restrict__ h1b, const int* __restrict__ row_start,
    const int* __restrict__ row_end, const int* __restrict__ csr_src,
    unsigned* __restrict__ agg2b) {
  int w = (blockIdx.x * 256 + threadIdx.x) >> 6;
  if (w >= N_NODES) return;
  int lane = threadIdx.x & 63;
  int rs = row_start[w], re = row_end[w];
  float ax = 0.f, ay = 0.f;
  for (int chunk = rs; chunk < re; chunk += 64) {
    int nv = min(64, re - chunk);
    int sv = (chunk + lane < re) ? csr_src[chunk + lane] : 0;
    int j = 0;
    for (; j + 4 <= nv; j += 4) {
      int s0 = __shfl(sv, j);
      int s1 = __shfl(sv, j + 1);
      int s2 = __shfl(sv, j + 2);
      int s3 = __shfl(sv, j + 3);
      unsigned u0 = h1b[(size_t)s0 * 64 + lane];
      unsigned u1 = h1b[(size_t)s1 * 64 + lane];
      unsigned u2 = h1b[(size_t)s2 * 64 + lane];
      unsigned u3 = h1b[(size_t)s3 * 64 + lane];
      ax += __uint_as_float(u0 << 16) + __uint_as_float(u1 << 16)
          + __uint_as_float(u2 << 16) + __uint_as_float(u3 << 16);
      ay += __uint_as_float(u0 & 0xFFFF0000u) + __uint_as_float(u1 & 0xFFFF0000u)
          + __uint_as_float(u2 & 0xFFFF0000u) + __uint_as_float(u3 & 0xFFFF0000u);
    }
    for (; j < nv; ++j) {
      int s0 = __shfl(sv, j);
      unsigned u0 = h1b[(size_t)s0 * 64 + lane];
      ax += __uint_as_float(u0 << 16);
      ay += __uint_as_float(u0 & 0xFFFF0000u);
    }
  }
  agg2b[(size_t)w * 64 + lane] = pack_bf16x2(ax, ay);
}

// ====== layer 2 dense + pool: MFMA GEMM [N x 256]@[256 x 128], relu+colsum ==
__global__ __launch_bounds__(256) void k_gemm_pool(
    const unsigned* __restrict__ agg2b_u, const unsigned* __restrict__ h1b_u,
    const float* __restrict__ W2_rel, const float* __restrict__ b2,
    const float* __restrict__ W2_root, float* __restrict__ gsum) {
  __shared__ unsigned short lds_w[32768];  // 64 KB: [8 ksteps][8 ftiles][64 lanes][8 bf16]

#pragma unroll
  for (int i = 0; i < 16; ++i) {
    int e = threadIdx.x + i * 256;          // 0..4095
    int L = e & 63, T = (e >> 6) & 7, K0 = e >> 9;
    int f = T * 16 + (L & 15);
    int k0 = K0 * 32 + ((L >> 4) << 3);
    const float* wsrc = (k0 < 128) ? (W2_rel + f * 128 + k0)
                                   : (W2_root + f * 128 + (k0 - 128));
    float4 w0 = *(const float4*)(wsrc);
    float4 w1 = *(const float4*)(wsrc + 4);
    unsigned* d = (unsigned*)&lds_w[e * 8];
    d[0] = pack_bf16x2(w0.x, w0.y);
    d[1] = pack_bf16x2(w0.z, w0.w);
    d[2] = pack_bf16x2(w1.x, w1.y);
    d[3] = pack_bf16x2(w1.z, w1.w);
  }
  __syncthreads();

  int lane = threadIdx.x & 63;
  int gw = blockIdx.x * 4 + (threadIdx.x >> 6);
  int lrow = lane & 15;
  int quad = lane >> 4;
  const unsigned short* agg2b = (const unsigned short*)agg2b_u;
  const unsigned short* h1b   = (const unsigned short*)h1b_u;

  float bias[8];
#pragma unroll
  for (int t = 0; t < 8; ++t) bias[t] = b2[t * 16 + lrow];

  float csum[8] = {0.f, 0.f, 0.f, 0.f, 0.f, 0.f, 0.f, 0.f};

  if (gw < NCHUNK) {
    int mbase = gw * 64;

    f32x4 acc[4][8];
#pragma unroll
    for (int mt = 0; mt < 4; ++mt)
#pragma unroll
      for (int t = 0; t < 8; ++t) acc[mt][t] = (f32x4){0.f, 0.f, 0.f, 0.f};

#pragma unroll
    for (int ks = 0; ks < 8; ++ks) {
      const unsigned short* abase = (ks < 4)
          ? (agg2b + ks * 32 + quad * 8)
          : (h1b + (ks - 4) * 32 + quad * 8);
      short8 afr[4];
#pragma unroll
      for (int mt = 0; mt < 4; ++mt) {
        int row = mbase + mt * 16 + lrow;
        row = min(row, N_NODES - 1);
        afr[mt] = *(const short8*)(abase + (size_t)row * 128);
      }
      const short8* wl = (const short8*)lds_w;
      short8 bfr[8];
#pragma unroll
      for (int t = 0; t < 8; ++t) bfr[t] = wl[(ks * 8 + t) * 64 + lane];
#pragma unroll
      for (int mt = 0; mt < 4; ++mt)
#pragma unroll
        for (int t = 0; t < 8; ++t)
          acc[mt][t] = __builtin_amdgcn_mfma_f32_16x16x32_bf16(
              afr[mt], bfr[t], acc[mt][t], 0, 0, 0);
    }

#pragma unroll
    for (int mt = 0; mt < 4; ++mt) {
      if (mbase + mt * 16 < N_NODES) {
#pragma unroll
        for (int t = 0; t < 8; ++t) {
          f32x4 v = acc[mt][t];
          float s = fmaxf(v.x + bias[t], 0.f) + fmaxf(v.y + bias[t], 0.f)
                  + fmaxf(v.z + bias[t], 0.f) + fmaxf(v.w + bias[t], 0.f);
          s += __shfl_xor(s, 16);
          s += __shfl_xor(s, 32);
          csum[t] += s;
        }
      }
    }
  }
  if (lane < 16) {
#pragma unroll
    for (int t = 0; t < 8; ++t) atomicAdd(gsum + t * 16 + lane, csum[t]);
  }
}

// ============ head: out = (gsum/N) @ Wlin.T + blin ============
__global__ void k_final(const float* __restrict__ gsum, const float* __restrict__ Wlin,
                        const float* __restrict__ blin, float* __restrict__ out) {
  int lane = threadIdx.x;  // 64 threads
  float g0 = gsum[lane];
  float g1 = gsum[lane + 64];
  float s0 = g0 * Wlin[lane]       + g1 * Wlin[lane + 64];
  float s1 = g0 * Wlin[128 + lane] + g1 * Wlin[192 + lane];
#pragma unroll
  for (int off = 32; off > 0; off >>= 1) {
    s0 += __shfl_down(s0, off);
    s1 += __shfl_down(s1, off);
  }
  if (lane == 0) {
    const float inv = 1.0f / (float)N_NODES;
    out[0] = s0 * inv + blin[0];
    out[1] = s1 * inv + blin[1];
  }
}

extern "C" void kernel_launch(void* const* d_in, const int* in_sizes, int n_in,
                              void* d_out, int out_size, void* d_ws, size_t ws_size,
                              hipStream_t stream) {
  const float* x       = (const float*)d_in[0];
  const int*   ei      = (const int*)d_in[1];
  const float* W1_rel  = (const float*)d_in[2];
  const float* b1      = (const float*)d_in[3];
  const float* W1_root = (const float*)d_in[4];
  const float* W2_rel  = (const float*)d_in[5];
  const float* b2      = (const float*)d_in[6];
  const float* W2_root = (const float*)d_in[7];
  const float* Wlin    = (const float*)d_in[8];
  const float* blin    = (const float*)d_in[9];
  const int* src = ei;            // edge_index[0]
  const int* dst = ei + N_EDGES;  // edge_index[1]
  float* out = (float*)d_out;

  // workspace layout (bytes):
  //   row_start     @0          : 400,000
  //   row_end       @400,000    : 400,000
  //   bucket_count  @800,000    : 1,024
  //   bucket_base   @801,024    : 1,024
  //   bucket_cursor @802,048    : 1,024
  //   gsum          @803,072    : 512
  //   csr_src       @803,584    : 6,400,000   -> 7,203,584
  //   ebuf (uint2)  @7,203,584  : 12,800,000  -> 20,003,584
  //   h1b           @20,003,584 : 25,600,000  -> 45,603,584
  //   agg2b         @45,603,584 : 25,600,000  -> 71,203,584
  //   agg1          @71,203,584 : 1,600,000   -> 72,803,584
  char* ws = (char*)d_ws;
  int*      row_start = (int*)(ws);
  int*      row_end   = (int*)(ws + 400000);
  int*      bucket_count  = (int*)(ws + 800000);
  int*      bucket_base   = (int*)(ws + 801024);
  int*      bucket_cursor = (int*)(ws + 802048);
  float*    gsum      = (float*)(ws + 803072);
  int*      csr_src   = (int*)(ws + 803584);
  uint2*    ebuf      = (uint2*)(ws + 7203584);
  unsigned* h1b       = (unsigned*)(ws + 20003584);
  unsigned* agg2b     = (unsigned*)(ws + 45603584);
  float*    agg1      = (float*)(ws + 71203584);

  hipMemsetAsync(bucket_count, 0, 1024, stream);
  hipMemsetAsync(gsum, 0, 512, stream);

  k_bhist<<<BF_BLOCKS, 256, 0, stream>>>(dst, bucket_count);
  k_bscan<<<1, 256, 0, stream>>>(bucket_count, bucket_base, bucket_cursor);
  k_bfill<<<BF_BLOCKS, 256, 0, stream>>>(src, dst, bucket_cursor, ebuf);
  k_fill2<<<NBUCK, 256, 0, stream>>>(ebuf, bucket_base, bucket_count,
                                     row_start, row_end, csr_src);
  k_pull4<<<(N_NODES + 255) / 256, 256, 0, stream>>>(x, row_start, row_end, csr_src, agg1);
  k_layer1<<<(N_NODES * 64 + 255) / 256, 256, 0, stream>>>(x, agg1, W1_rel, b1, W1_root, h1b);
  k_pull128<<<(N_NODES * 64 + 255) / 256, 256, 0, stream>>>(h1b, row_start, row_end, csr_src, agg2b);
  k_gemm_pool<<<(NCHUNK + 3) / 4, 256, 0, stream>>>(agg2b, h1b, W2_rel, b2, W2_root, gsum);
  k_final<<<1, 64, 0, stream>>>(gsum, Wlin, blin, out);
}

// Round 7
// 283.889 us; speedup vs baseline: 4.1017x; 1.0388x over previous
//
#include <hip/hip_runtime.h>
#include <cstddef>

#define N_NODES 100000
#define N_EDGES 1600000
#define NCHUNK 1563     // ceil(N_NODES / 64)
#define NBUCK 400
#define BUCK_NODES 250
#define EB_CAP 5000     // capacity per bucket; mean 4000, sigma 63 -> +15 sigma
#define BF_EDGES 4096   // edges per k_bfill block
#define BF_BLOCKS ((N_EDGES + BF_EDGES - 1) / BF_EDGES)   // 391

typedef __attribute__((ext_vector_type(8))) short short8;   // 8 bf16 = 4 VGPRs
typedef __attribute__((ext_vector_type(4))) float f32x4;

__device__ __forceinline__ unsigned pack_bf16x2(float a, float b) {
  unsigned ua = __float_as_uint(a); ua += 0x7FFFu + ((ua >> 16) & 1u);
  unsigned ub = __float_as_uint(b); ub += 0x7FFFu + ((ub >> 16) & 1u);
  return (ua >> 16) | (ub & 0xFFFF0000u);
}

// ============ init: replaces all memsets (one dispatch) ============
__global__ __launch_bounds__(512) void k_init(int* __restrict__ bucket_cursor,
                                              float* __restrict__ gsum) {
  int t = threadIdx.x;
  if (t < NBUCK) bucket_cursor[t] = t * EB_CAP;
  if (t < 128) gsum[t] = 0.0f;
}

// ============ CSR build pass 1: bucket-scatter edges (register-staged) ======
// Fixed-capacity bucket regions in ebuf; per-block LDS hist -> one global
// atomic per touched bucket reserves a contiguous sub-range (L2-mergeable
// writes, no cross-XCD line ping-pong).
__global__ __launch_bounds__(256) void k_bfill(const int* __restrict__ src,
                                               const int* __restrict__ dst,
                                               int* __restrict__ bucket_cursor,
                                               uint2* __restrict__ ebuf) {
  __shared__ int lh[NBUCK];
  __shared__ int sub_base[NBUCK];
  __shared__ int cur[NBUCK];
  int t = threadIdx.x;
  for (int b = t; b < NBUCK; b += 256) { lh[b] = 0; cur[b] = 0; }
  __syncthreads();
  int e0 = blockIdx.x * BF_EDGES;
  uint2 p[16];
#pragma unroll
  for (int i = 0; i < 16; ++i) {
    int e = e0 + i * 256 + t;
    p[i] = make_uint2(0u, 0xFFFFFFFFu);
    if (e < N_EDGES) {
      p[i] = make_uint2((unsigned)src[e], (unsigned)dst[e]);
      atomicAdd(&lh[p[i].y / BUCK_NODES], 1);
    }
  }
  __syncthreads();
  for (int b = t; b < NBUCK; b += 256)
    sub_base[b] = (lh[b] > 0) ? atomicAdd(&bucket_cursor[b], lh[b]) : 0;
  __syncthreads();
#pragma unroll
  for (int i = 0; i < 16; ++i) {
    if (p[i].y != 0xFFFFFFFFu) {
      int b = p[i].y / BUCK_NODES;
      int pos = sub_base[b] + atomicAdd(&cur[b], 1);
      if (pos < (b + 1) * EB_CAP) ebuf[pos] = p[i];  // overflow guard (15 sigma)
    }
  }
}

// ============ CSR build pass 2: one block per bucket ============
// Per-node degree hist + scan in LDS; scatter csr_src inside the bucket's
// contiguous region. nb comes from bucket_cursor (== base + count).
__global__ __launch_bounds__(256) void k_fill2(
    const uint2* __restrict__ ebuf, const int* __restrict__ bucket_cursor,
    int* __restrict__ row_start, int* __restrict__ row_end,
    int* __restrict__ csr_src) {
  __shared__ int cnt[256];
  __shared__ int start[256];
  __shared__ int partial[8];
  int t = threadIdx.x;
  int b = blockIdx.x;
  int base = b * EB_CAP;
  int nb = bucket_cursor[b] - base;
  int n0 = b * BUCK_NODES;
  cnt[t] = 0;
  __syncthreads();
  for (int i = t; i < nb; i += 256) {
    atomicAdd(&cnt[ebuf[base + i].y - n0], 1);
  }
  __syncthreads();
  if (t < 8) {
    int s = 0;
#pragma unroll
    for (int j = 0; j < 32; ++j) { start[t * 32 + j] = s; s += cnt[t * 32 + j]; }
    partial[t] = s;
  }
  __syncthreads();
  if (t == 0) {
    int s = 0;
#pragma unroll
    for (int j = 0; j < 8; ++j) { int tmp = partial[j]; partial[j] = s; s += tmp; }
  }
  __syncthreads();
  if (t < 8) {
    int off = partial[t];
#pragma unroll
    for (int j = 0; j < 32; ++j) start[t * 32 + j] += off;
  }
  __syncthreads();
  if (t < BUCK_NODES) {
    row_start[n0 + t] = base + start[t];
    cnt[t] = start[t];    // reuse as cursor
  }
  __syncthreads();
  for (int i = t; i < nb; i += 256) {
    uint2 e = ebuf[base + i];
    int p = atomicAdd(&cnt[e.y - n0], 1);
    csr_src[base + p] = (int)e.x;
  }
  __syncthreads();
  if (t < BUCK_NODES) row_end[n0 + t] = base + cnt[t];
}

// ============ layer 1: pull-aggregate x (Fin=4), thread per node ============
__global__ __launch_bounds__(256) void k_pull4(
    const float* __restrict__ x, const int* __restrict__ row_start,
    const int* __restrict__ row_end, const int* __restrict__ csr_src,
    float* __restrict__ agg1) {
  int n = blockIdx.x * 256 + threadIdx.x;
  if (n >= N_NODES) return;
  int rs = row_start[n], re = row_end[n];
  float4 acc = make_float4(0.f, 0.f, 0.f, 0.f);
  for (int i = rs; i < re; ++i) {
    int s = csr_src[i];
    float4 v = *(const float4*)(x + (size_t)s * 4);
    acc.x += v.x; acc.y += v.y; acc.z += v.z; acc.w += v.w;
  }
  *(float4*)(agg1 + (size_t)n * 4) = acc;
}

// ====== layer 1 dense: h1 = relu(...) computed fp32, stored bf16 rows ======
__global__ __launch_bounds__(256) void k_layer1(
    const float* __restrict__ x, const float* __restrict__ agg1,
    const float* __restrict__ W1_rel, const float* __restrict__ b1,
    const float* __restrict__ W1_root, unsigned* __restrict__ h1b) {
  int tid = blockIdx.x * 256 + threadIdx.x;
  if (tid >= N_NODES * 64) return;
  int node = tid >> 6;
  int f = (tid & 63) * 2;
  float4 a  = *(const float4*)(agg1 + node * 4);
  float4 xv = *(const float4*)(x + node * 4);
  float4 wr0 = *(const float4*)(W1_rel + f * 4);
  float4 wo0 = *(const float4*)(W1_root + f * 4);
  float4 wr1 = *(const float4*)(W1_rel + (f + 1) * 4);
  float4 wo1 = *(const float4*)(W1_root + (f + 1) * 4);
  float v0 = b1[f]
      + a.x * wr0.x + a.y * wr0.y + a.z * wr0.z + a.w * wr0.w
      + xv.x * wo0.x + xv.y * wo0.y + xv.z * wo0.z + xv.w * wo0.w;
  float v1 = b1[f + 1]
      + a.x * wr1.x + a.y * wr1.y + a.z * wr1.z + a.w * wr1.w
      + xv.x * wo1.x + xv.y * wo1.y + xv.z * wo1.z + xv.w * wo1.w;
  h1b[tid] = pack_bf16x2(fmaxf(v0, 0.f), fmaxf(v1, 0.f));
}

// ============ layer 2 aggregate: pull bf16 h1 rows, one WAVE per node ======
// 8 independent row-gathers in flight per batch.
__global__ __launch_bounds__(256) void k_pull128(
    const unsigned* __restrict__ h1b, const int* __restrict__ row_start,
    const int* __restrict__ row_end, const int* __restrict__ csr_src,
    unsigned* __restrict__ agg2b) {
  int w = (blockIdx.x * 256 + threadIdx.x) >> 6;
  if (w >= N_NODES) return;
  int lane = threadIdx.x & 63;
  int rs = row_start[w], re = row_end[w];
  float ax = 0.f, ay = 0.f;
  for (int chunk = rs; chunk < re; chunk += 64) {
    int nv = min(64, re - chunk);
    int sv = (chunk + lane < re) ? csr_src[chunk + lane] : 0;
    int j = 0;
    for (; j + 8 <= nv; j += 8) {
      int s0 = __shfl(sv, j);
      int s1 = __shfl(sv, j + 1);
      int s2 = __shfl(sv, j + 2);
      int s3 = __shfl(sv, j + 3);
      int s4 = __shfl(sv, j + 4);
      int s5 = __shfl(sv, j + 5);
      int s6 = __shfl(sv, j + 6);
      int s7 = __shfl(sv, j + 7);
      unsigned u0 = h1b[(size_t)s0 * 64 + lane];
      unsigned u1 = h1b[(size_t)s1 * 64 + lane];
      unsigned u2 = h1b[(size_t)s2 * 64 + lane];
      unsigned u3 = h1b[(size_t)s3 * 64 + lane];
      unsigned u4 = h1b[(size_t)s4 * 64 + lane];
      unsigned u5 = h1b[(size_t)s5 * 64 + lane];
      unsigned u6 = h1b[(size_t)s6 * 64 + lane];
      unsigned u7 = h1b[(size_t)s7 * 64 + lane];
      ax += __uint_as_float(u0 << 16) + __uint_as_float(u1 << 16)
          + __uint_as_float(u2 << 16) + __uint_as_float(u3 << 16)
          + __uint_as_float(u4 << 16) + __uint_as_float(u5 << 16)
          + __uint_as_float(u6 << 16) + __uint_as_float(u7 << 16);
      ay += __uint_as_float(u0 & 0xFFFF0000u) + __uint_as_float(u1 & 0xFFFF0000u)
          + __uint_as_float(u2 & 0xFFFF0000u) + __uint_as_float(u3 & 0xFFFF0000u)
          + __uint_as_float(u4 & 0xFFFF0000u) + __uint_as_float(u5 & 0xFFFF0000u)
          + __uint_as_float(u6 & 0xFFFF0000u) + __uint_as_float(u7 & 0xFFFF0000u);
    }
    for (; j < nv; ++j) {
      int s0 = __shfl(sv, j);
      unsigned u0 = h1b[(size_t)s0 * 64 + lane];
      ax += __uint_as_float(u0 << 16);
      ay += __uint_as_float(u0 & 0xFFFF0000u);
    }
  }
  agg2b[(size_t)w * 64 + lane] = pack_bf16x2(ax, ay);
}

// ====== layer 2 dense + pool: MFMA GEMM [N x 256]@[256 x 128], relu+colsum ==
__global__ __launch_bounds__(256) void k_gemm_pool(
    const unsigned* __restrict__ agg2b_u, const unsigned* __restrict__ h1b_u,
    const float* __restrict__ W2_rel, const float* __restrict__ b2,
    const float* __restrict__ W2_root, float* __restrict__ gsum) {
  __shared__ unsigned short lds_w[32768];  // 64 KB: [8 ksteps][8 ftiles][64 lanes][8 bf16]

#pragma unroll
  for (int i = 0; i < 16; ++i) {
    int e = threadIdx.x + i * 256;          // 0..4095
    int L = e & 63, T = (e >> 6) & 7, K0 = e >> 9;
    int f = T * 16 + (L & 15);
    int k0 = K0 * 32 + ((L >> 4) << 3);
    const float* wsrc = (k0 < 128) ? (W2_rel + f * 128 + k0)
                                   : (W2_root + f * 128 + (k0 - 128));
    float4 w0 = *(const float4*)(wsrc);
    float4 w1 = *(const float4*)(wsrc + 4);
    unsigned* d = (unsigned*)&lds_w[e * 8];
    d[0] = pack_bf16x2(w0.x, w0.y);
    d[1] = pack_bf16x2(w0.z, w0.w);
    d[2] = pack_bf16x2(w1.x, w1.y);
    d[3] = pack_bf16x2(w1.z, w1.w);
  }
  __syncthreads();

  int lane = threadIdx.x & 63;
  int gw = blockIdx.x * 4 + (threadIdx.x >> 6);
  int lrow = lane & 15;
  int quad = lane >> 4;
  const unsigned short* agg2b = (const unsigned short*)agg2b_u;
  const unsigned short* h1b   = (const unsigned short*)h1b_u;

  float bias[8];
#pragma unroll
  for (int t = 0; t < 8; ++t) bias[t] = b2[t * 16 + lrow];

  float csum[8] = {0.f, 0.f, 0.f, 0.f, 0.f, 0.f, 0.f, 0.f};

  if (gw < NCHUNK) {
    int mbase = gw * 64;

    f32x4 acc[4][8];
#pragma unroll
    for (int mt = 0; mt < 4; ++mt)
#pragma unroll
      for (int t = 0; t < 8; ++t) acc[mt][t] = (f32x4){0.f, 0.f, 0.f, 0.f};

#pragma unroll
    for (int ks = 0; ks < 8; ++ks) {
      const unsigned short* abase = (ks < 4)
          ? (agg2b + ks * 32 + quad * 8)
          : (h1b + (ks - 4) * 32 + quad * 8);
      short8 afr[4];
#pragma unroll
      for (int mt = 0; mt < 4; ++mt) {
        int row = mbase + mt * 16 + lrow;
        row = min(row, N_NODES - 1);
        afr[mt] = *(const short8*)(abase + (size_t)row * 128);
      }
      const short8* wl = (const short8*)lds_w;
      short8 bfr[8];
#pragma unroll
      for (int t = 0; t < 8; ++t) bfr[t] = wl[(ks * 8 + t) * 64 + lane];
#pragma unroll
      for (int mt = 0; mt < 4; ++mt)
#pragma unroll
        for (int t = 0; t < 8; ++t)
          acc[mt][t] = __builtin_amdgcn_mfma_f32_16x16x32_bf16(
              afr[mt], bfr[t], acc[mt][t], 0, 0, 0);
    }

#pragma unroll
    for (int mt = 0; mt < 4; ++mt) {
      if (mbase + mt * 16 < N_NODES) {
#pragma unroll
        for (int t = 0; t < 8; ++t) {
          f32x4 v = acc[mt][t];
          float s = fmaxf(v.x + bias[t], 0.f) + fmaxf(v.y + bias[t], 0.f)
                  + fmaxf(v.z + bias[t], 0.f) + fmaxf(v.w + bias[t], 0.f);
          s += __shfl_xor(s, 16);
          s += __shfl_xor(s, 32);
          csum[t] += s;
        }
      }
    }
  }
  if (lane < 16) {
#pragma unroll
    for (int t = 0; t < 8; ++t) atomicAdd(gsum + t * 16 + lane, csum[t]);
  }
}

// ============ head: out = (gsum/N) @ Wlin.T + blin ============
__global__ void k_final(const float* __restrict__ gsum, const float* __restrict__ Wlin,
                        const float* __restrict__ blin, float* __restrict__ out) {
  int lane = threadIdx.x;  // 64 threads
  float g0 = gsum[lane];
  float g1 = gsum[lane + 64];
  float s0 = g0 * Wlin[lane]       + g1 * Wlin[lane + 64];
  float s1 = g0 * Wlin[128 + lane] + g1 * Wlin[192 + lane];
#pragma unroll
  for (int off = 32; off > 0; off >>= 1) {
    s0 += __shfl_down(s0, off);
    s1 += __shfl_down(s1, off);
  }
  if (lane == 0) {
    const float inv = 1.0f / (float)N_NODES;
    out[0] = s0 * inv + blin[0];
    out[1] = s1 * inv + blin[1];
  }
}

extern "C" void kernel_launch(void* const* d_in, const int* in_sizes, int n_in,
                              void* d_out, int out_size, void* d_ws, size_t ws_size,
                              hipStream_t stream) {
  const float* x       = (const float*)d_in[0];
  const int*   ei      = (const int*)d_in[1];
  const float* W1_rel  = (const float*)d_in[2];
  const float* b1      = (const float*)d_in[3];
  const float* W1_root = (const float*)d_in[4];
  const float* W2_rel  = (const float*)d_in[5];
  const float* b2      = (const float*)d_in[6];
  const float* W2_root = (const float*)d_in[7];
  const float* Wlin    = (const float*)d_in[8];
  const float* blin    = (const float*)d_in[9];
  const int* src = ei;            // edge_index[0]
  const int* dst = ei + N_EDGES;  // edge_index[1]
  float* out = (float*)d_out;

  // workspace layout (bytes):
  //   row_start     @0          : 400,000
  //   row_end       @400,000    : 400,000
  //   bucket_cursor @800,000    : 1,600
  //   gsum          @801,600    : 512
  //   csr_src       @802,112    : 8,000,000   -> 8,802,112
  //   ebuf (uint2)  @8,802,112  : 16,000,000  -> 24,802,112
  //   h1b           @24,802,112 : 25,600,000  -> 50,402,112
  //   agg2b         @50,402,112 : 25,600,000  -> 76,002,112
  //   agg1          @76,002,112 : 1,600,000   -> 77,602,112
  char* ws = (char*)d_ws;
  int*      row_start     = (int*)(ws);
  int*      row_end       = (int*)(ws + 400000);
  int*      bucket_cursor = (int*)(ws + 800000);
  float*    gsum          = (float*)(ws + 801600);
  int*      csr_src       = (int*)(ws + 802112);
  uint2*    ebuf          = (uint2*)(ws + 8802112);
  unsigned* h1b           = (unsigned*)(ws + 24802112);
  unsigned* agg2b         = (unsigned*)(ws + 50402112);
  float*    agg1          = (float*)(ws + 76002112);

  k_init <<<1, 512, 0, stream>>>(bucket_cursor, gsum);
  k_bfill<<<BF_BLOCKS, 256, 0, stream>>>(src, dst, bucket_cursor, ebuf);
  k_fill2<<<NBUCK, 256, 0, stream>>>(ebuf, bucket_cursor, row_start, row_end, csr_src);
  k_pull4<<<(N_NODES + 255) / 256, 256, 0, stream>>>(x, row_start, row_end, csr_src, agg1);
  k_layer1<<<(N_NODES * 64 + 255) / 256, 256, 0, stream>>>(x, agg1, W1_rel, b1, W1_root, h1b);
  k_pull128<<<(N_NODES * 64 + 255) / 256, 256, 0, stream>>>(h1b, row_start, row_end, csr_src, agg2b);
  k_gemm_pool<<<(NCHUNK + 3) / 4, 256, 0, stream>>>(agg2b, h1b, W2_rel, b2, W2_root, gsum);
  k_final<<<1, 64, 0, stream>>>(gsum, Wlin, blin, out);
}